// Round 2
// baseline (787.496 us; speedup 1.0000x reference)
//
#include <hip/hip_runtime.h>

#define LMBDA 0.001f

// workspace layout (float offsets)
#define WS_A    0        // 64*256
#define WS_FY   16384    // 64*256
#define WS_H1   32768
#define WS_G1   36864
#define WS_RHS  40960
#define WS_GINV 45056
#define WS_HINV 49152
#define WS_M1   53248
#define WS_R2   57344
#define WS_R4   61440
// total 65536 floats = 256 KiB

// XOR swizzle: kills stride-64 same-bank column reads without padding
#define SIDX(i,k) (((i) << 6) | ((k) ^ ((i) & 31)))

// ---------------- Kernel 1: A = tx@fx, Fy = ty@fy  (64x5000 @ 5000x256) ----
// grid (8, 40): x: [0..3]=A col-tiles, [4..7]=Fy col-tiles; y: split-K over V
__global__ __launch_bounds__(256) void k1_gemm(
    const float* __restrict__ tx, const float* __restrict__ fx,
    const float* __restrict__ ty, const float* __restrict__ fy,
    float* __restrict__ wsA, float* __restrict__ wsFy)
{
    __shared__ float stx[64 * 65];
    __shared__ float sfx[64 * 65];
    const int tid = threadIdx.x;
    const int ti = tid >> 4, tj = tid & 15;
    const int mat = blockIdx.x >> 2;
    const int m0 = (blockIdx.x & 3) << 6;
    const float* __restrict__ T = mat ? ty : tx;
    const float* __restrict__ F = mat ? fy : fx;
    float* __restrict__ Out = mat ? wsFy : wsA;

    float acc[4][4];
    #pragma unroll
    for (int r = 0; r < 4; ++r)
        #pragma unroll
        for (int c = 0; c < 4; ++c) acc[r][c] = 0.f;

    for (int sc = blockIdx.y; sc * 64 < 5000; sc += gridDim.y) {
        const int v0 = sc << 6;
        int vlen = 5000 - v0; if (vlen > 64) vlen = 64;
        #pragma unroll
        for (int w = 0; w < 4; ++w) {
            const int fidx = tid + (w << 8);
            const int row = fidx >> 4, q = fidx & 15;
            const int vv = q << 2;
            if (vv < vlen) {   // stx[k][vv] = T[k*5000 + v0+vv]
                float4 val = *(const float4*)(T + (size_t)row * 5000 + v0 + vv);
                stx[row * 65 + vv + 0] = val.x;
                stx[row * 65 + vv + 1] = val.y;
                stx[row * 65 + vv + 2] = val.z;
                stx[row * 65 + vv + 3] = val.w;
            }
            if (row < vlen) {  // sfx[vv][m] = F[(v0+vv)*256 + m0+m]
                float4 val = *(const float4*)(F + (size_t)(v0 + row) * 256 + m0 + (q << 2));
                sfx[row * 65 + (q << 2) + 0] = val.x;
                sfx[row * 65 + (q << 2) + 1] = val.y;
                sfx[row * 65 + (q << 2) + 2] = val.z;
                sfx[row * 65 + (q << 2) + 3] = val.w;
            }
        }
        __syncthreads();
        for (int vv = 0; vv < vlen; ++vv) {
            float a[4], b[4];
            #pragma unroll
            for (int r = 0; r < 4; ++r) a[r] = stx[(4 * ti + r) * 65 + vv];
            #pragma unroll
            for (int c = 0; c < 4; ++c) b[c] = sfx[vv * 65 + 4 * tj + c];
            #pragma unroll
            for (int r = 0; r < 4; ++r)
                #pragma unroll
                for (int c = 0; c < 4; ++c)
                    acc[r][c] = fmaf(a[r], b[c], acc[r][c]);
        }
        __syncthreads();
    }
    #pragma unroll
    for (int r = 0; r < 4; ++r)
        #pragma unroll
        for (int c = 0; c < 4; ++c)
            atomicAdd(&Out[(4 * ti + r) * 256 + m0 + 4 * tj + c], acc[r][c]);
}

// ---------------- Kernel 2: small-matrix setup (one block, 256 thr) --------
// H1=sy^T sy; G1=A A^T; RHS=H1*(Fy A^T); invert {G1,H1,sx} via in-place GJ;
// R2=P^T Dx P, R4=P^T P, M1=G1+l*P^T Dx^2 P  (P=inv_sx)
__global__ __launch_bounds__(256) void k2_setup(
    const float* __restrict__ wsA, const float* __restrict__ wsFy,
    const float* __restrict__ sx, const float* __restrict__ sy,
    const float* __restrict__ ex, float* __restrict__ ws)
{
    __shared__ float B0[64 * 65];
    __shared__ float B1[64 * 65];
    __shared__ float B2[64 * 65];
    __shared__ float sF[3][64];
    __shared__ float sPv[3];
    __shared__ float sEx[64];
    const int tid = threadIdx.x;
    const int ti = tid >> 4, tj = tid & 15;

    // P0: S -> B0
    for (int idx = tid; idx < 4096; idx += 256)
        B0[(idx >> 6) * 65 + (idx & 63)] = sy[idx];
    __syncthreads();

    // P1: H1 = S^T S -> B1 and ws
    {
        float a[4][4];
        #pragma unroll
        for (int r = 0; r < 4; ++r)
            #pragma unroll
            for (int c = 0; c < 4; ++c) a[r][c] = 0.f;
        for (int k = 0; k < 64; ++k) {
            float av[4], bv[4];
            #pragma unroll
            for (int r = 0; r < 4; ++r) av[r] = B0[k * 65 + 4 * ti + r];
            #pragma unroll
            for (int c = 0; c < 4; ++c) bv[c] = B0[k * 65 + 4 * tj + c];
            #pragma unroll
            for (int r = 0; r < 4; ++r)
                #pragma unroll
                for (int c = 0; c < 4; ++c) a[r][c] = fmaf(av[r], bv[c], a[r][c]);
        }
        #pragma unroll
        for (int r = 0; r < 4; ++r)
            #pragma unroll
            for (int c = 0; c < 4; ++c) {
                B1[(4 * ti + r) * 65 + 4 * tj + c] = a[r][c];
                ws[WS_H1 + (4 * ti + r) * 64 + 4 * tj + c] = a[r][c];
            }
    }
    __syncthreads();

    // P2: G1 = A A^T -> B0 and ws (stage A in 64-col chunks)
    {
        float a[4][4];
        #pragma unroll
        for (int r = 0; r < 4; ++r)
            #pragma unroll
            for (int c = 0; c < 4; ++c) a[r][c] = 0.f;
        for (int ch = 0; ch < 4; ++ch) {
            for (int idx = tid; idx < 4096; idx += 256)
                B2[(idx >> 6) * 65 + (idx & 63)] = wsA[(idx >> 6) * 256 + (ch << 6) + (idx & 63)];
            __syncthreads();
            for (int mm = 0; mm < 64; ++mm) {
                float av[4], bv[4];
                #pragma unroll
                for (int r = 0; r < 4; ++r) av[r] = B2[(4 * ti + r) * 65 + mm];
                #pragma unroll
                for (int c = 0; c < 4; ++c) bv[c] = B2[(4 * tj + c) * 65 + mm];
                #pragma unroll
                for (int r = 0; r < 4; ++r)
                    #pragma unroll
                    for (int c = 0; c < 4; ++c) a[r][c] = fmaf(av[r], bv[c], a[r][c]);
            }
            __syncthreads();
        }
        #pragma unroll
        for (int r = 0; r < 4; ++r)
            #pragma unroll
            for (int c = 0; c < 4; ++c) {
                B0[(4 * ti + r) * 65 + 4 * tj + c] = a[r][c];
                ws[WS_G1 + (4 * ti + r) * 64 + 4 * tj + c] = a[r][c];
            }
    }
    __syncthreads();

    // P3: FyAT = Fy * A^T -> B2 ; then RHS = H1 * FyAT -> ws
    {
        float a[4][4];
        #pragma unroll
        for (int r = 0; r < 4; ++r)
            #pragma unroll
            for (int c = 0; c < 4; ++c) a[r][c] = 0.f;
        for (int m4 = 0; m4 < 256; m4 += 4) {
            float4 fv[4], av[4];
            #pragma unroll
            for (int r = 0; r < 4; ++r) fv[r] = *(const float4*)&wsFy[(4 * ti + r) * 256 + m4];
            #pragma unroll
            for (int c = 0; c < 4; ++c) av[c] = *(const float4*)&wsA[(4 * tj + c) * 256 + m4];
            #pragma unroll
            for (int r = 0; r < 4; ++r)
                #pragma unroll
                for (int c = 0; c < 4; ++c) {
                    a[r][c] = fmaf(fv[r].x, av[c].x, a[r][c]);
                    a[r][c] = fmaf(fv[r].y, av[c].y, a[r][c]);
                    a[r][c] = fmaf(fv[r].z, av[c].z, a[r][c]);
                    a[r][c] = fmaf(fv[r].w, av[c].w, a[r][c]);
                }
        }
        #pragma unroll
        for (int r = 0; r < 4; ++r)
            #pragma unroll
            for (int c = 0; c < 4; ++c) B2[(4 * ti + r) * 65 + 4 * tj + c] = a[r][c];
    }
    __syncthreads();
    {
        float a[4][4];
        #pragma unroll
        for (int r = 0; r < 4; ++r)
            #pragma unroll
            for (int c = 0; c < 4; ++c) a[r][c] = 0.f;
        for (int k = 0; k < 64; ++k) {
            float hv[4], tv[4];
            #pragma unroll
            for (int r = 0; r < 4; ++r) hv[r] = B1[(4 * ti + r) * 65 + k];
            #pragma unroll
            for (int c = 0; c < 4; ++c) tv[c] = B2[k * 65 + 4 * tj + c];
            #pragma unroll
            for (int r = 0; r < 4; ++r)
                #pragma unroll
                for (int c = 0; c < 4; ++c) a[r][c] = fmaf(hv[r], tv[c], a[r][c]);
        }
        #pragma unroll
        for (int r = 0; r < 4; ++r)
            #pragma unroll
            for (int c = 0; c < 4; ++c)
                ws[WS_RHS + (4 * ti + r) * 64 + 4 * tj + c] = a[r][c];
    }
    __syncthreads();

    // P4: sx -> B2 ; ex -> sEx
    for (int idx = tid; idx < 4096; idx += 256)
        B2[(idx >> 6) * 65 + (idx & 63)] = sx[idx];
    if (tid < 64) sEx[tid] = ex[tid];
    __syncthreads();

    // P5: in-place Gauss-Jordan inversion of B0(G1), B1(H1), B2(sx)
    // (all well-conditioned / near-identity: no pivoting needed)
    // NOTE: no pointer-array of LDS buffers — gfx950 rejects the static
    // initializer; select via ternary instead.
    for (int c = 0; c < 64; ++c) {
        if (tid < 3) {
            float* Mm = (tid == 0) ? B0 : ((tid == 1) ? B1 : B2);
            sPv[tid] = 1.0f / Mm[c * 65 + c];
        }
        if (tid < 192) {
            int m = tid >> 6, r = tid & 63;
            float* Mm = (m == 0) ? B0 : ((m == 1) ? B1 : B2);
            sF[m][r] = Mm[r * 65 + c];
        }
        __syncthreads();
        if (tid < 192) {
            int m = tid >> 6, j = tid & 63;
            float* Mm = (m == 0) ? B0 : ((m == 1) ? B1 : B2);
            float pv = sPv[m];
            Mm[c * 65 + j] = (j == c) ? pv : Mm[c * 65 + j] * pv;
        }
        __syncthreads();
        for (int idx = tid; idx < 3 * 4096; idx += 256) {
            int m = idx >> 12, rest = idx & 4095;
            int r = rest >> 6, j = rest & 63;
            if (r == c) continue;
            float* Mm = (m == 0) ? B0 : ((m == 1) ? B1 : B2);
            float f = sF[m][r];
            if (j == c) Mm[r * 65 + c] = -f * sPv[m];
            else        Mm[r * 65 + j] -= f * Mm[c * 65 + j];
        }
        __syncthreads();
    }
    // write Ginv (B0), Hinv (B1)
    for (int idx = tid; idx < 4096; idx += 256) {
        ws[WS_GINV + idx] = B0[(idx >> 6) * 65 + (idx & 63)];
        ws[WS_HINV + idx] = B1[(idx >> 6) * 65 + (idx & 63)];
    }
    __syncthreads();

    // P6: P = B2 = inv_sx;  R4 = P^T P, R2 = P^T Dx P, M1 = G1 + l*P^T Dx^2 P
    {
        float aR2[4][4], aR4[4][4], aT1[4][4];
        #pragma unroll
        for (int r = 0; r < 4; ++r)
            #pragma unroll
            for (int c = 0; c < 4; ++c) { aR2[r][c] = 0.f; aR4[r][c] = 0.f; aT1[r][c] = 0.f; }
        for (int k = 0; k < 64; ++k) {
            float e = sEx[k], e2 = e * e;
            float pi[4], pj[4];
            #pragma unroll
            for (int r = 0; r < 4; ++r) pi[r] = B2[k * 65 + 4 * ti + r];
            #pragma unroll
            for (int c = 0; c < 4; ++c) pj[c] = B2[k * 65 + 4 * tj + c];
            #pragma unroll
            for (int r = 0; r < 4; ++r)
                #pragma unroll
                for (int c = 0; c < 4; ++c) {
                    float p = pi[r] * pj[c];
                    aR4[r][c] += p;
                    aR2[r][c] = fmaf(e, p, aR2[r][c]);
                    aT1[r][c] = fmaf(e2, p, aT1[r][c]);
                }
        }
        #pragma unroll
        for (int r = 0; r < 4; ++r)
            #pragma unroll
            for (int c = 0; c < 4; ++c) {
                int o = (4 * ti + r) * 64 + 4 * tj + c;
                ws[WS_R4 + o] = aR4[r][c];
                ws[WS_R2 + o] = aR2[r][c];
                ws[WS_M1 + o] = ws[WS_G1 + o] + LMBDA * aT1[r][c];
            }
    }
}

// ---------------- Kernel 3: preconditioned Richardson solve (one block) ----
// op(X) = H1(X M1 - l D X R2) + D H1 l(D X R4 - X R2);  M^{-1}R = Hinv R Ginv
__global__ __launch_bounds__(256) void k3_solve(
    const float* __restrict__ ws, const float* __restrict__ ey_g,
    float* __restrict__ out)
{
    __shared__ float sX[4096];
    __shared__ float sR[4096];
    __shared__ float sT0[4096];
    __shared__ float sT1[4096];
    const int tid = threadIdx.x;
    const int ti = tid >> 4, tj = tid & 15;
    const float* __restrict__ RHSg = ws + WS_RHS;
    const float* __restrict__ Ginv = ws + WS_GINV;
    const float* __restrict__ Hinv = ws + WS_HINV;
    const float* __restrict__ M1g  = ws + WS_M1;
    const float* __restrict__ R2g  = ws + WS_R2;
    const float* __restrict__ R4g  = ws + WS_R4;
    const float* __restrict__ H1g  = ws + WS_H1;

    float eyr[4], leyr[4];
    #pragma unroll
    for (int r = 0; r < 4; ++r) { eyr[r] = ey_g[4 * ti + r]; leyr[r] = LMBDA * eyr[r]; }

    for (int idx = tid; idx < 4096; idx += 256) {
        int i = idx >> 6, j = idx & 63;
        sR[SIDX(i, j)] = RHSg[idx];
        sX[SIDX(i, j)] = 0.f;
    }
    __syncthreads();

    for (int it = 0; it < 5; ++it) {
        // T0 = R * Ginv
        {
            float a[4][4];
            #pragma unroll
            for (int r = 0; r < 4; ++r)
                #pragma unroll
                for (int c = 0; c < 4; ++c) a[r][c] = 0.f;
            for (int k = 0; k < 64; ++k) {
                float rv[4];
                #pragma unroll
                for (int r = 0; r < 4; ++r) rv[r] = sR[SIDX(4 * ti + r, k)];
                float4 gv = *(const float4*)&Ginv[k * 64 + 4 * tj];
                #pragma unroll
                for (int r = 0; r < 4; ++r) {
                    a[r][0] = fmaf(rv[r], gv.x, a[r][0]);
                    a[r][1] = fmaf(rv[r], gv.y, a[r][1]);
                    a[r][2] = fmaf(rv[r], gv.z, a[r][2]);
                    a[r][3] = fmaf(rv[r], gv.w, a[r][3]);
                }
            }
            #pragma unroll
            for (int r = 0; r < 4; ++r)
                #pragma unroll
                for (int c = 0; c < 4; ++c) sT0[SIDX(4 * ti + r, 4 * tj + c)] = a[r][c];
        }
        __syncthreads();
        // X += Hinv * T0 ; final iter: write out
        {
            float a[4][4];
            #pragma unroll
            for (int r = 0; r < 4; ++r)
                #pragma unroll
                for (int c = 0; c < 4; ++c) a[r][c] = 0.f;
            for (int k = 0; k < 64; ++k) {
                float hv[4], tv[4];
                #pragma unroll
                for (int r = 0; r < 4; ++r) hv[r] = Hinv[(4 * ti + r) * 64 + k];
                #pragma unroll
                for (int c = 0; c < 4; ++c) tv[c] = sT0[SIDX(k, 4 * tj + c)];
                #pragma unroll
                for (int r = 0; r < 4; ++r)
                    #pragma unroll
                    for (int c = 0; c < 4; ++c) a[r][c] = fmaf(hv[r], tv[c], a[r][c]);
            }
            #pragma unroll
            for (int r = 0; r < 4; ++r)
                #pragma unroll
                for (int c = 0; c < 4; ++c) {
                    int s = SIDX(4 * ti + r, 4 * tj + c);
                    float nx = sX[s] + a[r][c];
                    sX[s] = nx;
                    if (it == 4) out[(4 * ti + r) * 64 + 4 * tj + c] = nx;
                }
        }
        if (it == 4) break;
        __syncthreads();
        // E1 = X M1 - l D X R2 -> T0 ;  E2 = l(D X R4 - X R2) -> T1
        {
            float a1[4][4], a2[4][4];
            #pragma unroll
            for (int r = 0; r < 4; ++r)
                #pragma unroll
                for (int c = 0; c < 4; ++c) { a1[r][c] = 0.f; a2[r][c] = 0.f; }
            for (int k = 0; k < 64; ++k) {
                float xv[4];
                #pragma unroll
                for (int r = 0; r < 4; ++r) xv[r] = sX[SIDX(4 * ti + r, k)];
                float4 mv = *(const float4*)&M1g[k * 64 + 4 * tj];
                float4 qv = *(const float4*)&R2g[k * 64 + 4 * tj];
                float4 r4 = *(const float4*)&R4g[k * 64 + 4 * tj];
                float mvv[4] = {mv.x, mv.y, mv.z, mv.w};
                float qvv[4] = {qv.x, qv.y, qv.z, qv.w};
                float r4v[4] = {r4.x, r4.y, r4.z, r4.w};
                #pragma unroll
                for (int r = 0; r < 4; ++r)
                    #pragma unroll
                    for (int c = 0; c < 4; ++c) {
                        a1[r][c] = fmaf(xv[r], fmaf(-leyr[r], qvv[c], mvv[c]), a1[r][c]);
                        a2[r][c] = fmaf(xv[r], fmaf(eyr[r], r4v[c], -qvv[c]), a2[r][c]);
                    }
            }
            #pragma unroll
            for (int r = 0; r < 4; ++r)
                #pragma unroll
                for (int c = 0; c < 4; ++c) {
                    sT0[SIDX(4 * ti + r, 4 * tj + c)] = a1[r][c];
                    sT1[SIDX(4 * ti + r, 4 * tj + c)] = LMBDA * a2[r][c];
                }
        }
        __syncthreads();
        // R = rhs - H1*(T0 + D*T1)
        {
            float a[4][4];
            #pragma unroll
            for (int r = 0; r < 4; ++r)
                #pragma unroll
                for (int c = 0; c < 4; ++c) a[r][c] = 0.f;
            for (int k = 0; k < 64; ++k) {
                float hv[4];
                #pragma unroll
                for (int r = 0; r < 4; ++r) hv[r] = H1g[(4 * ti + r) * 64 + k];
                float t0v[4], t1v[4];
                #pragma unroll
                for (int c = 0; c < 4; ++c) {
                    t0v[c] = sT0[SIDX(k, 4 * tj + c)];
                    t1v[c] = sT1[SIDX(k, 4 * tj + c)];
                }
                #pragma unroll
                for (int r = 0; r < 4; ++r)
                    #pragma unroll
                    for (int c = 0; c < 4; ++c)
                        a[r][c] = fmaf(hv[r], fmaf(eyr[r], t1v[c], t0v[c]), a[r][c]);
            }
            #pragma unroll
            for (int r = 0; r < 4; ++r)
                #pragma unroll
                for (int c = 0; c < 4; ++c)
                    sR[SIDX(4 * ti + r, 4 * tj + c)] =
                        RHSg[(4 * ti + r) * 64 + 4 * tj + c] - a[r][c];
        }
        __syncthreads();
    }
}

extern "C" void kernel_launch(void* const* d_in, const int* in_sizes, int n_in,
                              void* d_out, int out_size, void* d_ws, size_t ws_size,
                              hipStream_t stream) {
    (void)in_sizes; (void)n_in; (void)out_size; (void)ws_size;
    const float* fx = (const float*)d_in[0];
    const float* fy = (const float*)d_in[1];
    const float* ex = (const float*)d_in[2];
    const float* ey = (const float*)d_in[3];
    const float* tx = (const float*)d_in[4];
    const float* ty = (const float*)d_in[5];
    const float* sx = (const float*)d_in[6];
    const float* sy = (const float*)d_in[7];
    float* ws = (float*)d_ws;
    float* out = (float*)d_out;

    // zero the atomic-accumulated A / Fy buffers (ws is poisoned each call)
    (void)hipMemsetAsync(d_ws, 0, 2 * 64 * 256 * sizeof(float), stream);
    k1_gemm<<<dim3(8, 40), 256, 0, stream>>>(tx, fx, ty, fy, ws + WS_A, ws + WS_FY);
    k2_setup<<<1, 256, 0, stream>>>(ws + WS_A, ws + WS_FY, sx, sy, ex, ws);
    k3_solve<<<1, 256, 0, stream>>>(ws, ey, out);
}

// Round 3
// 310.667 us; speedup vs baseline: 2.5349x; 2.5349x over previous
//
#include <hip/hip_runtime.h>

#define LMBDA 0.001f
#define NS_SPD 10   // Newton-Schulz iters for SPD H1/G1 (residual^(2^k))
#define NS_SX  6    // Newton-Schulz iters for sx (||I-sx||~0.8)
#define OUTER  6    // outer preconditioned-Richardson iterations

// workspace layout (float offsets)
#define WS_A    0        // 64*256
#define WS_FY   16384    // 64*256
#define WS_H1   32768
#define WS_G1   36864
#define WS_HINV 40960
#define WS_GINV 45056
#define WS_R2   49152
#define WS_R4   53248
#define WS_T1   57344
#define WS_FYAT 61440
// total 65536 floats = 256 KiB

#define LDP 68   // padded LDS leading dim: 16B-aligned rows, 2-way-max banks
// XOR swizzle for k3 buffers (as in R2 — verified conflict-benign)
#define SIDX(i,k) (((i) << 6) | ((k) ^ ((i) & 31)))

// ---------------- Kernel 1: A = tx@fx, Fy = ty@fy  (64x5000 @ 5000x256) ----
__global__ __launch_bounds__(256) void k1_gemm(
    const float* __restrict__ tx, const float* __restrict__ fx,
    const float* __restrict__ ty, const float* __restrict__ fy,
    float* __restrict__ wsA, float* __restrict__ wsFy)
{
    __shared__ float stx[64 * 65];
    __shared__ float sfx[64 * 65];
    const int tid = threadIdx.x;
    const int ti = tid >> 4, tj = tid & 15;
    const int mat = blockIdx.x >> 2;
    const int m0 = (blockIdx.x & 3) << 6;
    const float* __restrict__ T = mat ? ty : tx;
    const float* __restrict__ F = mat ? fy : fx;
    float* __restrict__ Out = mat ? wsFy : wsA;

    float acc[4][4];
    #pragma unroll
    for (int r = 0; r < 4; ++r)
        #pragma unroll
        for (int c = 0; c < 4; ++c) acc[r][c] = 0.f;

    for (int sc = blockIdx.y; sc * 64 < 5000; sc += gridDim.y) {
        const int v0 = sc << 6;
        int vlen = 5000 - v0; if (vlen > 64) vlen = 64;
        #pragma unroll
        for (int w = 0; w < 4; ++w) {
            const int fidx = tid + (w << 8);
            const int row = fidx >> 4, q = fidx & 15;
            const int vv = q << 2;
            if (vv < vlen) {
                float4 val = *(const float4*)(T + (size_t)row * 5000 + v0 + vv);
                stx[row * 65 + vv + 0] = val.x;
                stx[row * 65 + vv + 1] = val.y;
                stx[row * 65 + vv + 2] = val.z;
                stx[row * 65 + vv + 3] = val.w;
            }
            if (row < vlen) {
                float4 val = *(const float4*)(F + (size_t)(v0 + row) * 256 + m0 + (q << 2));
                sfx[row * 65 + (q << 2) + 0] = val.x;
                sfx[row * 65 + (q << 2) + 1] = val.y;
                sfx[row * 65 + (q << 2) + 2] = val.z;
                sfx[row * 65 + (q << 2) + 3] = val.w;
            }
        }
        __syncthreads();
        for (int vv = 0; vv < vlen; ++vv) {
            float a[4], b[4];
            #pragma unroll
            for (int r = 0; r < 4; ++r) a[r] = stx[(4 * ti + r) * 65 + vv];
            #pragma unroll
            for (int c = 0; c < 4; ++c) b[c] = sfx[vv * 65 + 4 * tj + c];
            #pragma unroll
            for (int r = 0; r < 4; ++r)
                #pragma unroll
                for (int c = 0; c < 4; ++c)
                    acc[r][c] = fmaf(a[r], b[c], acc[r][c]);
        }
        __syncthreads();
    }
    #pragma unroll
    for (int r = 0; r < 4; ++r)
        #pragma unroll
        for (int c = 0; c < 4; ++c)
            atomicAdd(&Out[(4 * ti + r) * 256 + m0 + 4 * tj + c], acc[r][c]);
}

// ---- Newton-Schulz in-LDS inversion: X <- X(2I - M X), X0 = alpha*I ------
// M, X, Y are 64x64 (leading dim LDP) LDS buffers. 3 barriers/iter.
__device__ __forceinline__ void ns_invert(float* M, float* X, float* Y,
                                          int iters, int ti, int tj,
                                          int tid, float alpha)
{
    for (int idx = tid; idx < 4096; idx += 256) {
        int i = idx >> 6, j = idx & 63;
        X[i * LDP + j] = (i == j) ? alpha : 0.f;
    }
    __syncthreads();
    for (int it = 0; it < iters; ++it) {
        // Y = M * X
        float y[4][4];
        #pragma unroll
        for (int r = 0; r < 4; ++r)
            #pragma unroll
            for (int c = 0; c < 4; ++c) y[r][c] = 0.f;
        for (int k = 0; k < 64; ++k) {
            float mv[4];
            #pragma unroll
            for (int r = 0; r < 4; ++r) mv[r] = M[(4 * ti + r) * LDP + k];
            float4 xv = *(const float4*)&X[k * LDP + 4 * tj];
            #pragma unroll
            for (int r = 0; r < 4; ++r) {
                y[r][0] = fmaf(mv[r], xv.x, y[r][0]);
                y[r][1] = fmaf(mv[r], xv.y, y[r][1]);
                y[r][2] = fmaf(mv[r], xv.z, y[r][2]);
                y[r][3] = fmaf(mv[r], xv.w, y[r][3]);
            }
        }
        #pragma unroll
        for (int r = 0; r < 4; ++r)
            #pragma unroll
            for (int c = 0; c < 4; ++c)
                Y[(4 * ti + r) * LDP + 4 * tj + c] = y[r][c];
        __syncthreads();
        // Z = X * Y ; X = 2X - Z
        float z[4][4];
        #pragma unroll
        for (int r = 0; r < 4; ++r)
            #pragma unroll
            for (int c = 0; c < 4; ++c) z[r][c] = 0.f;
        for (int k = 0; k < 64; ++k) {
            float xr[4];
            #pragma unroll
            for (int r = 0; r < 4; ++r) xr[r] = X[(4 * ti + r) * LDP + k];
            float4 yv = *(const float4*)&Y[k * LDP + 4 * tj];
            #pragma unroll
            for (int r = 0; r < 4; ++r) {
                z[r][0] = fmaf(xr[r], yv.x, z[r][0]);
                z[r][1] = fmaf(xr[r], yv.y, z[r][1]);
                z[r][2] = fmaf(xr[r], yv.z, z[r][2]);
                z[r][3] = fmaf(xr[r], yv.w, z[r][3]);
            }
        }
        __syncthreads();   // all reads of X done
        #pragma unroll
        for (int r = 0; r < 4; ++r)
            #pragma unroll
            for (int c = 0; c < 4; ++c) {
                int s = (4 * ti + r) * LDP + 4 * tj + c;
                X[s] = 2.f * X[s] - z[r][c];
            }
        __syncthreads();
    }
}

// ---------------- Kernel 2: 4 specialized blocks ---------------------------
// b0: H1=sy^T sy -> ws, NS-> Hinv     b1: G1=A A^T -> ws, NS-> Ginv
// b2: NS(sx)=P; R2=P^T Dx P, R4=P^T P, T1=P^T Dx^2 P -> ws
// b3: FyAT = Fy A^T -> ws
__global__ __launch_bounds__(256) void k2_prep(
    const float* __restrict__ wsA, const float* __restrict__ wsFy,
    const float* __restrict__ sx, const float* __restrict__ sy,
    const float* __restrict__ ex, float* __restrict__ ws)
{
    __shared__ __align__(16) float sA[64 * LDP];
    __shared__ __align__(16) float sM[64 * LDP];
    __shared__ __align__(16) float sX[64 * LDP];
    __shared__ float sRow[64];
    __shared__ float sAlpha;
    const int tid = threadIdx.x;
    const int ti = tid >> 4, tj = tid & 15;
    const int b = blockIdx.x;

    if (b == 0) {
        // stage sy row-major: sA[k*LDP+i] = sy[k,i]
        for (int idx = tid; idx < 1024; idx += 256) {
            int i = idx >> 4, j4 = (idx & 15) << 2;
            float4 v = *(const float4*)&sy[i * 64 + j4];
            *(float4*)&sA[i * LDP + j4] = v;
        }
        __syncthreads();
        // H1 = sy^T sy
        float a[4][4];
        #pragma unroll
        for (int r = 0; r < 4; ++r)
            #pragma unroll
            for (int c = 0; c < 4; ++c) a[r][c] = 0.f;
        for (int k = 0; k < 64; ++k) {
            float4 av = *(const float4*)&sA[k * LDP + 4 * ti];
            float4 bv = *(const float4*)&sA[k * LDP + 4 * tj];
            float avv[4] = {av.x, av.y, av.z, av.w};
            #pragma unroll
            for (int r = 0; r < 4; ++r) {
                a[r][0] = fmaf(avv[r], bv.x, a[r][0]);
                a[r][1] = fmaf(avv[r], bv.y, a[r][1]);
                a[r][2] = fmaf(avv[r], bv.z, a[r][2]);
                a[r][3] = fmaf(avv[r], bv.w, a[r][3]);
            }
        }
        #pragma unroll
        for (int r = 0; r < 4; ++r)
            #pragma unroll
            for (int c = 0; c < 4; ++c) {
                sM[(4 * ti + r) * LDP + 4 * tj + c] = a[r][c];
                ws[WS_H1 + (4 * ti + r) * 64 + 4 * tj + c] = a[r][c];
            }
        __syncthreads();
        // Gershgorin scale
        if (tid < 64) {
            float s = 0.f;
            for (int j = 0; j < 64; ++j) s += fabsf(sM[tid * LDP + j]);
            sRow[tid] = s;
        }
        __syncthreads();
        if (tid == 0) {
            float mx = 0.f;
            for (int i = 0; i < 64; ++i) mx = fmaxf(mx, sRow[i]);
            sAlpha = 1.0f / mx;
        }
        __syncthreads();
        ns_invert(sM, sX, sA, NS_SPD, ti, tj, tid, sAlpha);
        for (int idx = tid; idx < 1024; idx += 256) {
            int i = idx >> 4, j4 = (idx & 15) << 2;
            *(float4*)&ws[WS_HINV + i * 64 + j4] = *(const float4*)&sX[i * LDP + j4];
        }
    } else if (b == 1) {
        // G1 = A A^T over 4 chunks (transposed staging: both operands f4)
        float a[4][4];
        #pragma unroll
        for (int r = 0; r < 4; ++r)
            #pragma unroll
            for (int c = 0; c < 4; ++c) a[r][c] = 0.f;
        for (int ch = 0; ch < 4; ++ch) {
            for (int idx = tid; idx < 1024; idx += 256) {
                int i = idx >> 4, m4 = (idx & 15) << 2;
                float4 v = *(const float4*)&wsA[i * 256 + (ch << 6) + m4];
                sA[(m4 + 0) * LDP + i] = v.x;
                sA[(m4 + 1) * LDP + i] = v.y;
                sA[(m4 + 2) * LDP + i] = v.z;
                sA[(m4 + 3) * LDP + i] = v.w;
            }
            __syncthreads();
            for (int m = 0; m < 64; ++m) {
                float4 av = *(const float4*)&sA[m * LDP + 4 * ti];
                float4 bv = *(const float4*)&sA[m * LDP + 4 * tj];
                float avv[4] = {av.x, av.y, av.z, av.w};
                #pragma unroll
                for (int r = 0; r < 4; ++r) {
                    a[r][0] = fmaf(avv[r], bv.x, a[r][0]);
                    a[r][1] = fmaf(avv[r], bv.y, a[r][1]);
                    a[r][2] = fmaf(avv[r], bv.z, a[r][2]);
                    a[r][3] = fmaf(avv[r], bv.w, a[r][3]);
                }
            }
            __syncthreads();
        }
        #pragma unroll
        for (int r = 0; r < 4; ++r)
            #pragma unroll
            for (int c = 0; c < 4; ++c) {
                sM[(4 * ti + r) * LDP + 4 * tj + c] = a[r][c];
                ws[WS_G1 + (4 * ti + r) * 64 + 4 * tj + c] = a[r][c];
            }
        __syncthreads();
        if (tid < 64) {
            float s = 0.f;
            for (int j = 0; j < 64; ++j) s += fabsf(sM[tid * LDP + j]);
            sRow[tid] = s;
        }
        __syncthreads();
        if (tid == 0) {
            float mx = 0.f;
            for (int i = 0; i < 64; ++i) mx = fmaxf(mx, sRow[i]);
            sAlpha = 1.0f / mx;
        }
        __syncthreads();
        ns_invert(sM, sX, sA, NS_SPD, ti, tj, tid, sAlpha);
        for (int idx = tid; idx < 1024; idx += 256) {
            int i = idx >> 4, j4 = (idx & 15) << 2;
            *(float4*)&ws[WS_GINV + i * 64 + j4] = *(const float4*)&sX[i * LDP + j4];
        }
    } else if (b == 2) {
        // P = inv(sx) via NS (X0 = I); then R2/R4/T1
        for (int idx = tid; idx < 1024; idx += 256) {
            int i = idx >> 4, j4 = (idx & 15) << 2;
            float4 v = *(const float4*)&sx[i * 64 + j4];
            *(float4*)&sM[i * LDP + j4] = v;
        }
        if (tid < 64) sRow[tid] = ex[tid];
        __syncthreads();
        ns_invert(sM, sX, sA, NS_SX, ti, tj, tid, 1.0f);
        // R4 = P^T P, R2 = P^T Dx P, T1 = P^T Dx^2 P
        float aR2[4][4], aR4[4][4], aT1[4][4];
        #pragma unroll
        for (int r = 0; r < 4; ++r)
            #pragma unroll
            for (int c = 0; c < 4; ++c) { aR2[r][c] = 0.f; aR4[r][c] = 0.f; aT1[r][c] = 0.f; }
        for (int k = 0; k < 64; ++k) {
            float e = sRow[k], e2 = e * e;
            float4 av = *(const float4*)&sX[k * LDP + 4 * ti];
            float4 bv = *(const float4*)&sX[k * LDP + 4 * tj];
            float avv[4] = {av.x, av.y, av.z, av.w};
            float bvv[4] = {bv.x, bv.y, bv.z, bv.w};
            #pragma unroll
            for (int r = 0; r < 4; ++r)
                #pragma unroll
                for (int c = 0; c < 4; ++c) {
                    float p = avv[r] * bvv[c];
                    aR4[r][c] += p;
                    aR2[r][c] = fmaf(e, p, aR2[r][c]);
                    aT1[r][c] = fmaf(e2, p, aT1[r][c]);
                }
        }
        #pragma unroll
        for (int r = 0; r < 4; ++r)
            #pragma unroll
            for (int c = 0; c < 4; ++c) {
                int o = (4 * ti + r) * 64 + 4 * tj + c;
                ws[WS_R2 + o] = aR2[r][c];
                ws[WS_R4 + o] = aR4[r][c];
                ws[WS_T1 + o] = aT1[r][c];
            }
    } else {
        // FyAT = Fy A^T over 4 chunks (double transposed staging)
        float a[4][4];
        #pragma unroll
        for (int r = 0; r < 4; ++r)
            #pragma unroll
            for (int c = 0; c < 4; ++c) a[r][c] = 0.f;
        for (int ch = 0; ch < 4; ++ch) {
            for (int idx = tid; idx < 1024; idx += 256) {
                int i = idx >> 4, m4 = (idx & 15) << 2;
                float4 v = *(const float4*)&wsFy[i * 256 + (ch << 6) + m4];
                sA[(m4 + 0) * LDP + i] = v.x;
                sA[(m4 + 1) * LDP + i] = v.y;
                sA[(m4 + 2) * LDP + i] = v.z;
                sA[(m4 + 3) * LDP + i] = v.w;
                float4 w = *(const float4*)&wsA[i * 256 + (ch << 6) + m4];
                sM[(m4 + 0) * LDP + i] = w.x;
                sM[(m4 + 1) * LDP + i] = w.y;
                sM[(m4 + 2) * LDP + i] = w.z;
                sM[(m4 + 3) * LDP + i] = w.w;
            }
            __syncthreads();
            for (int m = 0; m < 64; ++m) {
                float4 fv = *(const float4*)&sA[m * LDP + 4 * ti];
                float4 av = *(const float4*)&sM[m * LDP + 4 * tj];
                float fvv[4] = {fv.x, fv.y, fv.z, fv.w};
                #pragma unroll
                for (int r = 0; r < 4; ++r) {
                    a[r][0] = fmaf(fvv[r], av.x, a[r][0]);
                    a[r][1] = fmaf(fvv[r], av.y, a[r][1]);
                    a[r][2] = fmaf(fvv[r], av.z, a[r][2]);
                    a[r][3] = fmaf(fvv[r], av.w, a[r][3]);
                }
            }
            __syncthreads();
        }
        #pragma unroll
        for (int r = 0; r < 4; ++r)
            #pragma unroll
            for (int c = 0; c < 4; ++c)
                ws[WS_FYAT + (4 * ti + r) * 64 + 4 * tj + c] = a[r][c];
    }
}

// ---------------- Kernel 3: preconditioned Richardson solve (one block) ----
__global__ __launch_bounds__(256) void k3_solve(
    const float* __restrict__ ws, const float* __restrict__ ey_g,
    float* __restrict__ out)
{
    __shared__ float sX[4096];
    __shared__ float sR[4096];
    __shared__ float sT0[4096];
    __shared__ float sT1[4096];
    const int tid = threadIdx.x;
    const int ti = tid >> 4, tj = tid & 15;
    const float* __restrict__ H1g  = ws + WS_H1;
    const float* __restrict__ G1g  = ws + WS_G1;
    const float* __restrict__ T1g  = ws + WS_T1;
    const float* __restrict__ Ginv = ws + WS_GINV;
    const float* __restrict__ Hinv = ws + WS_HINV;
    const float* __restrict__ R2g  = ws + WS_R2;
    const float* __restrict__ R4g  = ws + WS_R4;
    const float* __restrict__ FyAT = ws + WS_FYAT;

    float4 eyv = *(const float4*)&ey_g[4 * ti];
    float eyr[4] = {eyv.x, eyv.y, eyv.z, eyv.w};
    float leyr[4];
    #pragma unroll
    for (int r = 0; r < 4; ++r) leyr[r] = LMBDA * eyr[r];

    // prologue: rhs = H1 * FyAT (H1 symmetric -> f4 row reads), kept in regs
    float rhs[4][4];
    #pragma unroll
    for (int r = 0; r < 4; ++r)
        #pragma unroll
        for (int c = 0; c < 4; ++c) rhs[r][c] = 0.f;
    for (int k = 0; k < 64; ++k) {
        float4 hv = *(const float4*)&H1g[k * 64 + 4 * ti];
        float4 tv = *(const float4*)&FyAT[k * 64 + 4 * tj];
        float hvv[4] = {hv.x, hv.y, hv.z, hv.w};
        #pragma unroll
        for (int r = 0; r < 4; ++r) {
            rhs[r][0] = fmaf(hvv[r], tv.x, rhs[r][0]);
            rhs[r][1] = fmaf(hvv[r], tv.y, rhs[r][1]);
            rhs[r][2] = fmaf(hvv[r], tv.z, rhs[r][2]);
            rhs[r][3] = fmaf(hvv[r], tv.w, rhs[r][3]);
        }
    }
    #pragma unroll
    for (int r = 0; r < 4; ++r)
        #pragma unroll
        for (int c = 0; c < 4; ++c) {
            sR[SIDX(4 * ti + r, 4 * tj + c)] = rhs[r][c];
            sX[SIDX(4 * ti + r, 4 * tj + c)] = 0.f;
        }
    __syncthreads();

    for (int it = 0; it < OUTER; ++it) {
        // T0 = R * Ginv
        {
            float a[4][4];
            #pragma unroll
            for (int r = 0; r < 4; ++r)
                #pragma unroll
                for (int c = 0; c < 4; ++c) a[r][c] = 0.f;
            for (int k = 0; k < 64; ++k) {
                float rv[4];
                #pragma unroll
                for (int r = 0; r < 4; ++r) rv[r] = sR[SIDX(4 * ti + r, k)];
                float4 gv = *(const float4*)&Ginv[k * 64 + 4 * tj];
                #pragma unroll
                for (int r = 0; r < 4; ++r) {
                    a[r][0] = fmaf(rv[r], gv.x, a[r][0]);
                    a[r][1] = fmaf(rv[r], gv.y, a[r][1]);
                    a[r][2] = fmaf(rv[r], gv.z, a[r][2]);
                    a[r][3] = fmaf(rv[r], gv.w, a[r][3]);
                }
            }
            #pragma unroll
            for (int r = 0; r < 4; ++r)
                #pragma unroll
                for (int c = 0; c < 4; ++c) sT0[SIDX(4 * ti + r, 4 * tj + c)] = a[r][c];
        }
        __syncthreads();
        // X += Hinv * T0 (Hinv symmetric -> f4 row reads)
        {
            float a[4][4];
            #pragma unroll
            for (int r = 0; r < 4; ++r)
                #pragma unroll
                for (int c = 0; c < 4; ++c) a[r][c] = 0.f;
            for (int k = 0; k < 64; ++k) {
                float4 hv = *(const float4*)&Hinv[k * 64 + 4 * ti];
                float hvv[4] = {hv.x, hv.y, hv.z, hv.w};
                float tv[4];
                #pragma unroll
                for (int c = 0; c < 4; ++c) tv[c] = sT0[SIDX(k, 4 * tj + c)];
                #pragma unroll
                for (int r = 0; r < 4; ++r)
                    #pragma unroll
                    for (int c = 0; c < 4; ++c) a[r][c] = fmaf(hvv[r], tv[c], a[r][c]);
            }
            #pragma unroll
            for (int r = 0; r < 4; ++r)
                #pragma unroll
                for (int c = 0; c < 4; ++c) {
                    int s = SIDX(4 * ti + r, 4 * tj + c);
                    float nx = sX[s] + a[r][c];
                    sX[s] = nx;
                    if (it == OUTER - 1) out[(4 * ti + r) * 64 + 4 * tj + c] = nx;
                }
        }
        if (it == OUTER - 1) break;
        __syncthreads();
        // E1 = X M1 - l D X R2 -> T0 ; E2 = l(D X R4 - X R2) -> T1, M1=G1+l*T1g
        {
            float a1[4][4], a2[4][4];
            #pragma unroll
            for (int r = 0; r < 4; ++r)
                #pragma unroll
                for (int c = 0; c < 4; ++c) { a1[r][c] = 0.f; a2[r][c] = 0.f; }
            for (int k = 0; k < 64; ++k) {
                float xv[4];
                #pragma unroll
                for (int r = 0; r < 4; ++r) xv[r] = sX[SIDX(4 * ti + r, k)];
                float4 g1 = *(const float4*)&G1g[k * 64 + 4 * tj];
                float4 t1 = *(const float4*)&T1g[k * 64 + 4 * tj];
                float4 qv = *(const float4*)&R2g[k * 64 + 4 * tj];
                float4 r4 = *(const float4*)&R4g[k * 64 + 4 * tj];
                float mvv[4] = {fmaf(LMBDA, t1.x, g1.x), fmaf(LMBDA, t1.y, g1.y),
                                fmaf(LMBDA, t1.z, g1.z), fmaf(LMBDA, t1.w, g1.w)};
                float qvv[4] = {qv.x, qv.y, qv.z, qv.w};
                float r4v[4] = {r4.x, r4.y, r4.z, r4.w};
                #pragma unroll
                for (int r = 0; r < 4; ++r)
                    #pragma unroll
                    for (int c = 0; c < 4; ++c) {
                        a1[r][c] = fmaf(xv[r], fmaf(-leyr[r], qvv[c], mvv[c]), a1[r][c]);
                        a2[r][c] = fmaf(xv[r], fmaf(eyr[r], r4v[c], -qvv[c]), a2[r][c]);
                    }
            }
            #pragma unroll
            for (int r = 0; r < 4; ++r)
                #pragma unroll
                for (int c = 0; c < 4; ++c) {
                    sT0[SIDX(4 * ti + r, 4 * tj + c)] = a1[r][c];
                    sT1[SIDX(4 * ti + r, 4 * tj + c)] = LMBDA * a2[r][c];
                }
        }
        __syncthreads();
        // R = rhs - H1*(T0 + D.T1)  (H1 symmetric -> f4 row reads)
        {
            float a[4][4];
            #pragma unroll
            for (int r = 0; r < 4; ++r)
                #pragma unroll
                for (int c = 0; c < 4; ++c) a[r][c] = 0.f;
            for (int k = 0; k < 64; ++k) {
                float4 hv = *(const float4*)&H1g[k * 64 + 4 * ti];
                float hvv[4] = {hv.x, hv.y, hv.z, hv.w};
                float t0v[4], t1v[4];
                #pragma unroll
                for (int c = 0; c < 4; ++c) {
                    t0v[c] = sT0[SIDX(k, 4 * tj + c)];
                    t1v[c] = sT1[SIDX(k, 4 * tj + c)];
                }
                #pragma unroll
                for (int r = 0; r < 4; ++r)
                    #pragma unroll
                    for (int c = 0; c < 4; ++c)
                        a[r][c] = fmaf(hvv[r], fmaf(eyr[r], t1v[c], t0v[c]), a[r][c]);
            }
            #pragma unroll
            for (int r = 0; r < 4; ++r)
                #pragma unroll
                for (int c = 0; c < 4; ++c)
                    sR[SIDX(4 * ti + r, 4 * tj + c)] = rhs[r][c] - a[r][c];
        }
        __syncthreads();
    }
}

extern "C" void kernel_launch(void* const* d_in, const int* in_sizes, int n_in,
                              void* d_out, int out_size, void* d_ws, size_t ws_size,
                              hipStream_t stream) {
    (void)in_sizes; (void)n_in; (void)out_size; (void)ws_size;
    const float* fx = (const float*)d_in[0];
    const float* fy = (const float*)d_in[1];
    const float* ex = (const float*)d_in[2];
    const float* ey = (const float*)d_in[3];
    const float* tx = (const float*)d_in[4];
    const float* ty = (const float*)d_in[5];
    const float* sx = (const float*)d_in[6];
    const float* sy = (const float*)d_in[7];
    float* ws = (float*)d_ws;
    float* out = (float*)d_out;

    (void)hipMemsetAsync(d_ws, 0, 2 * 64 * 256 * sizeof(float), stream);
    k1_gemm<<<dim3(8, 40), 256, 0, stream>>>(tx, fx, ty, fy, ws + WS_A, ws + WS_FY);
    k2_prep<<<4, 256, 0, stream>>>(ws + WS_A, ws + WS_FY, sx, sy, ex, ws);
    k3_solve<<<1, 256, 0, stream>>>(ws, ey, out);
}